// Round 16
// baseline (94.934 us; speedup 1.0000x reference)
//
#include <hip/hip_runtime.h>

typedef _Float16 f16x8 __attribute__((ext_vector_type(8)));
typedef float f32x4 __attribute__((ext_vector_type(4)));

#define NB 8192
#define DD 32
#define PER 25
#define STRH 272   // halfs per row of h0L/h1L planes

// Compiler-only ordering fence (no hardware wait).
#define FENCE_C() do { asm volatile("" ::: "memory"); \
                       __builtin_amdgcn_sched_barrier(0); } while (0)
// Hardware LDS drain: REQUIRED at every same-wave LDS write->read handoff
// (round-7 lesson: compiler order alone races nondeterministically).
#define FENCE_HW() do { asm volatile("s_waitcnt lgkmcnt(0)" ::: "memory"); \
                        __builtin_amdgcn_sched_barrier(0); } while (0)

__device__ __forceinline__ float rcp_f(float x) { return __builtin_amdgcn_rcpf(x); }
__device__ __forceinline__ float gelu_f(float x) {
    float a = -1.5957691216057308f * (x + 0.044715f * x * x * x);
    return x * rcp_f(1.0f + __expf(a));
}
__device__ __forceinline__ float softplus_f(float x) {
    return (x > 20.0f) ? x : __logf(1.0f + __expf(x));
}
__device__ __forceinline__ int cntf(int d) {
    return (d <= 0) ? 0 : ((d <= 8) ? 9 * d : 72 + 8 * (d - 8));
}
__device__ __forceinline__ int porig(int u) {
    int d = (u < 72) ? (u / 9 + 1) : ((u - 72) / 8 + 9);
    int s = (u < 72) ? (u % 9) : ((u - 72) % 8);
    return s * 31 + (d - 1);
}

// ---- quad-local cross-lane via DPP (VALU pipe, no LDS traffic) ----
template<int CTRL>
__device__ __forceinline__ float qperm(float v) {
    return __int_as_float(__builtin_amdgcn_update_dpp(
        0, __float_as_int(v), CTRL, 0xF, 0xF, true));
}
__device__ __forceinline__ float qsum2(float v) {
    v += qperm<0xB1>(v);
    v += qperm<0x4E>(v);
    return v;
}
__device__ __forceinline__ float qmax2(float v) {
    v = fmaxf(v, qperm<0xB1>(v));
    v = fmaxf(v, qperm<0x4E>(v));
    return v;
}
__device__ __forceinline__ float qscan(float v, int p) {
    float t = qperm<0x90>(v);
    float c = v + ((p >= 1) ? t : 0.0f);
    float t2 = qperm<0x44>(c);
    return c + ((p >= 2) ? t2 : 0.0f);
}
__device__ __forceinline__ float sel4(float r0, float r1, float r2, float r3, int m) {
    float lo = (m & 1) ? r1 : r0;
    float hi = (m & 1) ? r3 : r2;
    return (m & 2) ? hi : lo;
}

// Pack all weights into MFMA B-fragment layout (f16, masks baked in, zero padding).
__global__ void prep_kernel(const float* __restrict__ W0, const float* __restrict__ b0,
                            const float* __restrict__ W1, const float* __restrict__ b1,
                            const float* __restrict__ Wout, const float* __restrict__ bout,
                            _Float16* __restrict__ W0F, _Float16* __restrict__ W1F,
                            _Float16* __restrict__ WoutF,
                            float* __restrict__ b0F, float* __restrict__ b1F,
                            float* __restrict__ boutF)
{
    const int total = 16384 + 131072 + 262144 + 512 + 512 + 1024;  // 411648
    for (int e = blockIdx.x * blockDim.x + threadIdx.x; e < total;
         e += gridDim.x * blockDim.x) {
        if (e < 16384) {
            int i = e >> 9, r = e & 511, lane = r >> 3, j = r & 7;
            int c = lane & 15, k = ((lane >> 4) << 3) + j;
            int nn = cntf(i) - cntf(i - 1);
            float v = 0.0f;
            if (c < nn && k < i) v = W0[k * 256 + (c * 31 + i - 1)];
            W0F[e] = (_Float16)v;
        } else if (e < 16384 + 131072) {
            int m = e - 16384;
            int i = m >> 12, r = m & 4095, kt = r >> 9, r2 = r & 511;
            int lane = r2 >> 3, j = r2 & 7;
            int c = lane & 15, kpos = kt * 32 + ((lane >> 4) << 3) + j;
            int nn = cntf(i) - cntf(i - 1), chi = cntf(i);
            float v = 0.0f;
            if (c < nn && kpos < chi) v = W1[porig(kpos) * 256 + (c * 31 + i - 1)];
            W1F[m] = (_Float16)v;
        } else if (e < 16384 + 131072 + 262144) {
            int m = e - (16384 + 131072);
            int i = m >> 13, r = m & 8191, ct = r >> 12, r2 = r & 4095;
            int kt = r2 >> 9, r3 = r2 & 511, lane = r3 >> 3, j = r3 & 7;
            int par = ct * 16 + (lane & 15), kpos = kt * 32 + ((lane >> 4) << 3) + j;
            int chi = cntf(i);
            float v = 0.0f;
            if (par < 25 && kpos < chi) v = Wout[(i * 25 + par) * 256 + porig(kpos)];
            WoutF[m] = (_Float16)v;
        } else if (e < 409600 + 512) {
            int m = e - 409600;
            int i = m >> 4, c = m & 15;
            int nn = cntf(i) - cntf(i - 1);
            b0F[m] = (c < nn) ? b0[c * 31 + i - 1] : 0.0f;
        } else if (e < 410112 + 512) {
            int m = e - 410112;
            int i = m >> 4, c = m & 15;
            int nn = cntf(i) - cntf(i - 1);
            b1F[m] = (c < nn) ? b1[c * 31 + i - 1] : 0.0f;
        } else {
            int m = e - 410624;
            int i = m >> 5, c = m & 31;
            boutF[m] = (c < 25) ? bout[i * 25 + c] : 0.0f;
        }
    }
}

// One wave per block; 16 rows per wave, all 32 AR steps, MACs on the matrix pipe.
// h0/h1 in LDS (frag-readable, XOR-swizzled). Spline cross-lane is all-DPP.
// FULLY SHADOW-PIPELINED: Phase A's MFMA, and the FROZEN-TILE MFMAs of Phases
// B and C for the NEXT step, all run inside this step's spline shadow; only
// boundary tiles (1-2) remain after each fence.
__global__ __launch_bounds__(64, 1) void inv_kernel(
    const float* __restrict__ z, const float* __restrict__ W0raw,
    const _Float16* __restrict__ W0F, const _Float16* __restrict__ W1F,
    const _Float16* __restrict__ WoutF,
    const float* __restrict__ b0F, const float* __restrict__ b1F,
    const float* __restrict__ boutF,
    const int* __restrict__ tstep_p,
    float* __restrict__ xout, float* __restrict__ ldj)
{
    __shared__ float zs[16 * 33];              // z tile  [16 rows][33] (padded)
    __shared__ float xs[16 * 33];              // x state [16 rows][33] (padded)
    __shared__ float ps[16 * 33];              // spline params per row (padded)
    __shared__ __align__(16) _Float16 h0L[16 * STRH];   // h0 state, frag layout
    __shared__ __align__(16) _Float16 h1L[16 * STRH];   // h1 state, frag layout

    const int l = threadIdx.x;
    const int c16 = l & 15;              // C/D col, B col, A row selector
    const int g = l >> 4;                // k-group
    const int row0 = blockIdx.x * 16;

    for (int idx = l; idx < 512; idx += 64) {
        int r = idx >> 5, c = idx & 31;
        zs[r * 33 + c] = z[row0 * 32 + idx];
    }
    {   // zero h0L/h1L (u32 stores)
        unsigned int* p0 = (unsigned int*)h0L;
        unsigned int* p1 = (unsigned int*)h1L;
        for (int idx = l; idx < 16 * STRH / 2; idx += 64) { p0[idx] = 0u; p1[idx] = 0u; }
    }

    f16x8 xfrag;                         // A-frag of x: row=c16, k=g*8+j
#pragma unroll
    for (int j = 0; j < 8; ++j) xfrag[j] = (_Float16)0.0f;

    const float alpha = fminf(fmaxf(((float)(*tstep_p)) / 10000.0f, 0.0f), 1.0f);
    const float oma = 1.0f - alpha;
    const float dxoff = logf(expm1f(0.9999f));   // DX_OFF (once, precise)
    const int fbase = c16 * STRH + ((g ^ (c16 & 3)) << 3);   // frag-read base

    float ldreg = 0.0f;

    // double-buffered Phase-A weights + biases; pipelined state
    f16x8 wa2[2];
    float b0v2[2], b1v2[2], boA2[2], boB2[2];
    float w0i2[2];                       // raw W0 row for the rank-1 correction
    f32x4 accA;                          // next step's A-MFMA partial
    f32x4 accB, accC0, accC1;            // next step's frozen-tile partials
    f32x4 xi4;                           // x_i broadcast to this lane's 4 rows
    f16x8 wb_r[8], wc_r[2][8];           // CURRENT step's B/C frags (loaded in
                                         // the PREVIOUS step's shadow)
    wa2[0] = *(const f16x8*)&W0F[l * 8];
    b0v2[0] = b0F[c16];
    b1v2[0] = b1F[c16];
    boA2[0] = boutF[c16];
    boB2[0] = boutF[16 + c16];
    w0i2[0] = 0.0f;
#pragma unroll
    for (int q = 0; q < 4; ++q) {
        accA[q] = 0.0f; xi4[q] = 0.0f;
        accB[q] = 0.0f; accC0[q] = 0.0f; accC1[q] = 0.0f;
    }
    // step-0 frags (unused at i=0 since chi=0, but keeps state defined)
#pragma unroll
    for (int kt = 0; kt < 8; ++kt)
        wb_r[kt] = *(const f16x8*)&W1F[kt * 512 + l * 8];
#pragma unroll
    for (int ct = 0; ct < 2; ++ct)
#pragma unroll
        for (int kt = 0; kt < 8; ++kt)
            wc_r[ct][kt] = *(const f16x8*)&WoutF[ct * 4096 + kt * 512 + l * 8];

    FENCE_HW();   // zero-init / zs staging -> loop reads

#pragma unroll 1
    for (int ib = 0; ib < DD; ib += 2) {
#pragma unroll
        for (int ph = 0; ph < 2; ++ph) {
            const int i = ib + ph;
            const int clo = cntf(i - 1);
            const int chi = cntf(i);
            const int nn = chi - clo;        // 0 at i=0, else 8 or 9
            const int nfz = clo >> 5;        // tiles fully frozen (done in shadow)
            const int ip = (i + 1 < DD) ? (i + 1) : (DD - 1);

            // hoist zs read off the post-fence spline critical path
            const float zi = zs[(l >> 2) * 33 + i];

            // prefetch next step's A-weights + biases + raw-W0 correction row
            wa2[ph ^ 1] = *(const f16x8*)&W0F[ip * 512 + l * 8];
            b0v2[ph ^ 1] = b0F[ip * 16 + c16];
            b1v2[ph ^ 1] = b1F[ip * 16 + c16];
            boA2[ph ^ 1] = boutF[ip * 32 + c16];
            boB2[ph ^ 1] = boutF[ip * 32 + 16 + c16];
            {   // W0[k=i][c16*31 + i] (unit index for step i+1, slot c16); clamp OOB
                int widx = c16 * 31 + i;
                widx = (widx > 255) ? 255 : widx;
                w0i2[ph ^ 1] = W0raw[i * 256 + widx];
            }

            // ---- Phase A (pipelined): accA from last step + rank-1 x_{i-1} term ----
            if (nn > 0) {
                float bb = b0v2[ph];
                float w0i = w0i2[ph];
                if (c16 < nn) {
                    const int col = clo + c16;
#pragma unroll
                    for (int q = 0; q < 4; ++q) {
                        float v = accA[q] + xi4[q] * w0i + bb;
                        int row = g * 4 + q;
                        int phys = (col & ~31) | ((col & 31) ^ (8 * (row & 3)));
                        h0L[row * STRH + phys] = (_Float16)gelu_f(v);
                    }
                }
            }
            FENCE_HW();   // h0L boundary writes -> Phase B boundary reads

            // ---- Phase B (boundary tiles only; frozen part already in accB) ----
            if (nn > 0) {
#pragma unroll
                for (int kt = 0; kt < 8; ++kt) {
                    if (kt >= nfz && kt * 32 < chi) {
                        f16x8 af = *(const f16x8*)&h0L[fbase + kt * 32];
                        accB = __builtin_amdgcn_mfma_f32_16x16x32_f16(af, wb_r[kt], accB, 0, 0, 0);
                    }
                }
                float bb = b1v2[ph];
                if (c16 < nn) {
                    const int col = clo + c16;
#pragma unroll
                    for (int q = 0; q < 4; ++q) {
                        int row = g * 4 + q;
                        int phys = (col & ~31) | ((col & 31) ^ (8 * (row & 3)));
                        h1L[row * STRH + phys] = (_Float16)gelu_f(accB[q] + bb);
                    }
                }
            }
            FENCE_HW();   // h1L boundary writes -> Phase C boundary reads

            // ---- Phase C (boundary tiles only; frozen part already in accC*) ----
            {
#pragma unroll
                for (int kt = 0; kt < 8; ++kt) {
                    if (kt >= nfz && kt * 32 < chi) {
                        f16x8 af = *(const f16x8*)&h1L[fbase + kt * 32];
                        accC0 = __builtin_amdgcn_mfma_f32_16x16x32_f16(af, wc_r[0][kt], accC0, 0, 0, 0);
                        accC1 = __builtin_amdgcn_mfma_f32_16x16x32_f16(af, wc_r[1][kt], accC1, 0, 0, 0);
                    }
                }
                float boA = boA2[ph], boB = boB2[ph];
#pragma unroll
                for (int q = 0; q < 4; ++q)
                    ps[(g * 4 + q) * 33 + c16] = accC0[q] + boA;
                if (16 + c16 < 25) {
#pragma unroll
                    for (int q = 0; q < 4; ++q)
                        ps[(g * 4 + q) * 33 + 16 + c16] = accC1[q] + boB;
                }
            }

            // ---- pipelined A-MFMA for NEXT step (register-only; spline overlap) ----
            {
                f32x4 zz;
#pragma unroll
                for (int q = 0; q < 4; ++q) zz[q] = 0.0f;
                accA = __builtin_amdgcn_mfma_f32_16x16x32_f16(xfrag, wa2[ph ^ 1], zz, 0, 0, 0);
            }
            FENCE_HW();   // ps writes -> spline reads

            // ---- SHADOW for next step: load its B/C frags; frozen-tile MFMAs.
            //      All overlapped with the spline below (no dependencies).
#pragma unroll
            for (int kt = 0; kt < 8; ++kt)
                wb_r[kt] = *(const f16x8*)&W1F[ip * 4096 + kt * 512 + l * 8];
#pragma unroll
            for (int ct = 0; ct < 2; ++ct)
#pragma unroll
                for (int kt = 0; kt < 8; ++kt)
                    wc_r[ct][kt] = *(const f16x8*)&WoutF[ip * 8192 + ct * 4096 + kt * 512 + l * 8];
            {
                const int nfzN = chi >> 5;   // frozen tiles for step i+1
#pragma unroll
                for (int q = 0; q < 4; ++q) { accB[q] = 0.0f; accC0[q] = 0.0f; accC1[q] = 0.0f; }
#pragma unroll
                for (int kt = 0; kt < 8; ++kt) {
                    if (kt < nfzN) {
                        f16x8 a0 = *(const f16x8*)&h0L[fbase + kt * 32];
                        accB = __builtin_amdgcn_mfma_f32_16x16x32_f16(a0, wb_r[kt], accB, 0, 0, 0);
                        f16x8 a1 = *(const f16x8*)&h1L[fbase + kt * 32];
                        accC0 = __builtin_amdgcn_mfma_f32_16x16x32_f16(a1, wc_r[0][kt], accC0, 0, 0, 0);
                        accC1 = __builtin_amdgcn_mfma_f32_16x16x32_f16(a1, wc_r[1][kt], accC1, 0, 0, 0);
                    }
                }
            }

            // ---- Spline inverse: 4 lanes per row, all-DPP cross-lane ----
            float xv_sel;
            {
                const int r4 = l >> 2;          // row 0..15
                const int p  = l & 3;           // sub-lane in quad

                const float* bp = &ps[r4 * 33];
                float w_a = bp[p],      w_b = bp[4 + p];
                float h_a = bp[8 + p],  h_b = bp[12 + p];
                float d_a = bp[16 + p], d_b = bp[20 + p], d_cin = bp[24];

                // widths softmax chain (2 bins per lane); 2nd max-shift dropped
                float m_w = qmax2(fmaxf(w_a, w_b));
                float ewa = __expf(w_a - m_w), ewb = __expf(w_b - m_w);
                float rsw = rcp_f(qsum2(ewa + ewb));
                float bwa = oma * 1.25f + alpha * (ewa * rsw * 9.92f + 0.001f);
                float bwb = oma * 1.25f + alpha * (ewb * rsw * 9.92f + 0.001f);
                float scw = 10.0f * rcp_f(qsum2(bwa + bwb));
                bwa *= scw; bwb *= scw;
                float e2wa = __expf(bwa), e2wb = __expf(bwb);
                float rs2w = rcp_f(qsum2(e2wa + e2wb));
                float wdt_a = e2wa * rs2w * 9.9992f + 1e-4f;
                float wdt_b = e2wb * rs2w * 9.9992f + 1e-4f;

                // heights softmax chain
                float m_h = qmax2(fmaxf(h_a, h_b));
                float eha = __expf(h_a - m_h), ehb = __expf(h_b - m_h);
                float rsh = rcp_f(qsum2(eha + ehb));
                float bha = oma * 1.25f + alpha * (eha * rsh * 9.92f + 0.001f);
                float bhb = oma * 1.25f + alpha * (ehb * rsh * 9.92f + 0.001f);
                float sch = 10.0f * rcp_f(qsum2(bha + bhb));
                bha *= sch; bhb *= sch;
                float e2ha = __expf(bha), e2hb = __expf(bhb);
                float rs2h = rcp_f(qsum2(e2ha + e2hb));
                float hgt_a = e2ha * rs2h * 9.9992f + 1e-4f;
                float hgt_b = e2hb * rs2h * 9.9992f + 1e-4f;

                // slopes
                float dsl_a = softplus_f(oma + alpha * (softplus_f(d_a) + 0.001f) + dxoff) + 1e-4f;
                float dsl_b = softplus_f(oma + alpha * (softplus_f(d_b) + 0.001f) + dxoff) + 1e-4f;
                float dsl_c = softplus_f(oma + alpha * (softplus_f(d_cin) + 0.001f) + dxoff) + 1e-4f;

                // inclusive cumsums over 8 bins (DPP quad scans; b-half += a-total)
                float ca  = qscan(wdt_a, p);
                float cb  = qscan(wdt_b, p) + qperm<0xFF>(ca);
                float cha = qscan(hgt_a, p);
                float chb = qscan(hgt_b, p) + qperm<0xFF>(cha);

                // materialize all quad elements per lane (reg m holds elem p^m)
                float wdA1 = qperm<0xB1>(wdt_a), wdA2 = qperm<0x4E>(wdt_a), wdA3 = qperm<0x1B>(wdt_a);
                float wdB1 = qperm<0xB1>(wdt_b), wdB2 = qperm<0x4E>(wdt_b), wdB3 = qperm<0x1B>(wdt_b);
                float hgA1 = qperm<0xB1>(hgt_a), hgA2 = qperm<0x4E>(hgt_a), hgA3 = qperm<0x1B>(hgt_a);
                float hgB1 = qperm<0xB1>(hgt_b), hgB2 = qperm<0x4E>(hgt_b), hgB3 = qperm<0x1B>(hgt_b);
                float dsA1 = qperm<0xB1>(dsl_a), dsA2 = qperm<0x4E>(dsl_a), dsA3 = qperm<0x1B>(dsl_a);
                float dsB1 = qperm<0xB1>(dsl_b), dsB2 = qperm<0x4E>(dsl_b), dsB3 = qperm<0x1B>(dsl_b);
                float caA1 = qperm<0xB1>(ca),    caA2 = qperm<0x4E>(ca),    caA3 = qperm<0x1B>(ca);
                float caB1 = qperm<0xB1>(cb),    caB2 = qperm<0x4E>(cb),    caB3 = qperm<0x1B>(cb);
                float chA1 = qperm<0xB1>(cha),   chA2 = qperm<0x4E>(cha),   chA3 = qperm<0x1B>(cha);
                float chB1 = qperm<0xB1>(chb),   chB2 = qperm<0x4E>(chb),   chB3 = qperm<0x1B>(chb);

                const bool inr = (zi >= -5.0f) && (zi <= 5.0f);
                const float yc = fminf(fmaxf(zi, -5.0f), 5.0f);

                // bin index: count knots yp[e]<=yc over e=0..6 (exclude bin-7 knot)
                float ch7 = qperm<0xFF>(chb);
                int cnt = 0;
                cnt += (yc >= cha  - 5.0f); cnt += (yc >= chA1 - 5.0f);
                cnt += (yc >= chA2 - 5.0f); cnt += (yc >= chA3 - 5.0f);
                cnt += (yc >= chb  - 5.0f); cnt += (yc >= chB1 - 5.0f);
                cnt += (yc >= chB2 - 5.0f); cnt += (yc >= chB3 - 5.0f);
                int idx = cnt - ((yc >= ch7 - 5.0f) ? 1 : 0);   // 0..7

                // gather knot quantities via register select trees (no bpermute)
                int mA = (idx & 3) ^ p;
                bool hiH = (idx >= 4);
                float wk = hiH ? sel4(wdt_b, wdB1, wdB2, wdB3, mA)
                               : sel4(wdt_a, wdA1, wdA2, wdA3, mA);
                float hk = hiH ? sel4(hgt_b, hgB1, hgB2, hgB3, mA)
                               : sel4(hgt_a, hgA1, hgA2, hgA3, mA);
                float dk = hiH ? sel4(dsl_b, dsB1, dsB2, dsB3, mA)
                               : sel4(dsl_a, dsA1, dsA2, dsA3, mA);
                int j1 = idx + 1;
                int mJ = (j1 & 3) ^ p;
                float d1A = sel4(dsl_a, dsA1, dsA2, dsA3, mJ);
                float d1B = sel4(dsl_b, dsB1, dsB2, dsB3, mJ);
                float dk1 = (j1 < 4) ? d1A : ((j1 < 8) ? d1B : dsl_c);
                int im1 = idx - 1;
                int mM = (im1 & 3) ^ p;
                float cwm = (im1 < 4) ? sel4(ca, caA1, caA2, caA3, mM)
                                      : sel4(cb, caB1, caB2, caB3, mM);
                float chm = (im1 < 4) ? sel4(cha, chA1, chA2, chA3, mM)
                                      : sel4(chb, chB1, chB2, chB3, mM);
                float xk = (idx == 0) ? -5.0f : (cwm - 5.0f);
                float yk = (idx == 0) ? -5.0f : (chm - 5.0f);

                // rational-quadratic inverse (redundant on the quad)
                float s_ = hk * rcp_f(wk);
                float tt = yc - yk;
                float coef = dk1 + dk - 2.0f * s_;
                float aa = hk * (s_ - dk) + tt * coef;
                float bb = hk * dk - tt * coef;
                float cc = -s_ * tt;
                float disc = bb * bb - 4.0f * aa * cc;
                float xi = 2.0f * cc * rcp_f(-bb - __builtin_amdgcn_sqrtf(disc));
                float xv = xi * wk + xk;
                float z1 = xi * (1.0f - xi);
                float den = s_ + coef * z1;
                float omxi = 1.0f - xi;
                float num = dk1 * xi * xi + 2.0f * s_ * z1 + dk * omxi * omxi;
                float ld = __logf(den * den * rcp_f(s_ * s_ * num));  // fused 3-log

                xv_sel = inr ? xv : zi;
                ldreg += inr ? ld : 0.0f;
                if (p == 0) xs[(l >> 2) * 33 + i] = xv_sel;
            }

            // broadcast new x_i: rank-1 correction rows (xi4) + xfrag update
            {
#pragma unroll
                for (int q = 0; q < 4; ++q)
                    xi4[q] = __shfl(xv_sel, (g * 4 + q) << 2);
                float xnew = __shfl(xv_sel, (l & 15) << 2);
                if (g == (i >> 3)) {
#pragma unroll
                    for (int j = 0; j < 8; ++j)
                        if (j == (i & 7)) xfrag[j] = (_Float16)xnew;
                }
            }
            FENCE_C();
        }
    }

    FENCE_HW();   // xs writes -> output reads
    for (int idx = l; idx < 512; idx += 64) {
        int r = idx >> 5, c = idx & 31;
        xout[row0 * 32 + idx] = xs[r * 33 + c];
    }
    if ((l & 3) == 0) ldj[row0 + (l >> 2)] = ldreg;
}

extern "C" void kernel_launch(void* const* d_in, const int* in_sizes, int n_in,
                              void* d_out, int out_size, void* d_ws, size_t ws_size,
                              hipStream_t stream)
{
    const float* z    = (const float*)d_in[0];
    const float* W0   = (const float*)d_in[1];
    const float* b0   = (const float*)d_in[2];
    const float* W1   = (const float*)d_in[3];
    const float* b1   = (const float*)d_in[4];
    const float* Wout = (const float*)d_in[5];
    const float* bout = (const float*)d_in[6];
    const int* tstep  = (const int*)d_in[8];

    float* out  = (float*)d_out;
    float* xout = out;                 // x_fin, B x D
    float* ldj  = out + NB * DD;       // ldj, B

    _Float16* W0F   = (_Float16*)d_ws;            // 16384 halfs
    _Float16* W1F   = W0F + 16384;                // 131072 halfs
    _Float16* WoutF = W1F + 131072;               // 262144 halfs
    float* b0F  = (float*)(WoutF + 262144);       // 512 f32
    float* b1F  = b0F + 512;                      // 512 f32
    float* boutF = b1F + 512;                     // 1024 f32

    prep_kernel<<<1608, 256, 0, stream>>>(W0, b0, W1, b1, Wout, bout,
                                          W0F, W1F, WoutF, b0F, b1F, boutF);
    inv_kernel<<<NB / 16, 64, 0, stream>>>(z, W0, W0F, W1F, WoutF, b0F, b1F, boutF,
                                           tstep, xout, ldj);
}

// Round 17
// 82.776 us; speedup vs baseline: 1.1469x; 1.1469x over previous
//
#include <hip/hip_runtime.h>

typedef _Float16 f16x8 __attribute__((ext_vector_type(8)));
typedef float f32x4 __attribute__((ext_vector_type(4)));

#define NB 8192
#define DD 32
#define PER 25
#define STRH 272   // halfs per row of h0L/h1L planes

// Compiler-only ordering fence (no hardware wait).
#define FENCE_C() do { asm volatile("" ::: "memory"); \
                       __builtin_amdgcn_sched_barrier(0); } while (0)
// Hardware LDS drain: REQUIRED at every same-wave LDS write->read handoff
// (round-7 lesson: compiler order alone races nondeterministically).
#define FENCE_HW() do { asm volatile("s_waitcnt lgkmcnt(0)" ::: "memory"); \
                        __builtin_amdgcn_sched_barrier(0); } while (0)

__device__ __forceinline__ float rcp_f(float x) { return __builtin_amdgcn_rcpf(x); }
__device__ __forceinline__ float gelu_f(float x) {
    float a = -1.5957691216057308f * (x + 0.044715f * x * x * x);
    return x * rcp_f(1.0f + __expf(a));
}
__device__ __forceinline__ float softplus_f(float x) {
    return (x > 20.0f) ? x : __logf(1.0f + __expf(x));
}
__device__ __forceinline__ int cntf(int d) {
    return (d <= 0) ? 0 : ((d <= 8) ? 9 * d : 72 + 8 * (d - 8));
}
__device__ __forceinline__ int porig(int u) {
    int d = (u < 72) ? (u / 9 + 1) : ((u - 72) / 8 + 9);
    int s = (u < 72) ? (u % 9) : ((u - 72) % 8);
    return s * 31 + (d - 1);
}

// ---- quad-local cross-lane via DPP (VALU pipe, no LDS traffic) ----
template<int CTRL>
__device__ __forceinline__ float qperm(float v) {
    return __int_as_float(__builtin_amdgcn_update_dpp(
        0, __float_as_int(v), CTRL, 0xF, 0xF, true));
}
__device__ __forceinline__ float qsum2(float v) {
    v += qperm<0xB1>(v);
    v += qperm<0x4E>(v);
    return v;
}
__device__ __forceinline__ float qmax2(float v) {
    v = fmaxf(v, qperm<0xB1>(v));
    v = fmaxf(v, qperm<0x4E>(v));
    return v;
}
__device__ __forceinline__ float qscan(float v, int p) {
    float t = qperm<0x90>(v);
    float c = v + ((p >= 1) ? t : 0.0f);
    float t2 = qperm<0x44>(c);
    return c + ((p >= 2) ? t2 : 0.0f);
}
__device__ __forceinline__ float sel4(float r0, float r1, float r2, float r3, int m) {
    float lo = (m & 1) ? r1 : r0;
    float hi = (m & 1) ? r3 : r2;
    return (m & 2) ? hi : lo;
}

// Pack all weights into MFMA B-fragment layout (f16, masks baked in, zero padding).
__global__ void prep_kernel(const float* __restrict__ W0, const float* __restrict__ b0,
                            const float* __restrict__ W1, const float* __restrict__ b1,
                            const float* __restrict__ Wout, const float* __restrict__ bout,
                            _Float16* __restrict__ W0F, _Float16* __restrict__ W1F,
                            _Float16* __restrict__ WoutF,
                            float* __restrict__ b0F, float* __restrict__ b1F,
                            float* __restrict__ boutF)
{
    const int total = 16384 + 131072 + 262144 + 512 + 512 + 1024;  // 411648
    for (int e = blockIdx.x * blockDim.x + threadIdx.x; e < total;
         e += gridDim.x * blockDim.x) {
        if (e < 16384) {
            int i = e >> 9, r = e & 511, lane = r >> 3, j = r & 7;
            int c = lane & 15, k = ((lane >> 4) << 3) + j;
            int nn = cntf(i) - cntf(i - 1);
            float v = 0.0f;
            if (c < nn && k < i) v = W0[k * 256 + (c * 31 + i - 1)];
            W0F[e] = (_Float16)v;
        } else if (e < 16384 + 131072) {
            int m = e - 16384;
            int i = m >> 12, r = m & 4095, kt = r >> 9, r2 = r & 511;
            int lane = r2 >> 3, j = r2 & 7;
            int c = lane & 15, kpos = kt * 32 + ((lane >> 4) << 3) + j;
            int nn = cntf(i) - cntf(i - 1), chi = cntf(i);
            float v = 0.0f;
            if (c < nn && kpos < chi) v = W1[porig(kpos) * 256 + (c * 31 + i - 1)];
            W1F[m] = (_Float16)v;
        } else if (e < 16384 + 131072 + 262144) {
            int m = e - (16384 + 131072);
            int i = m >> 13, r = m & 8191, ct = r >> 12, r2 = r & 4095;
            int kt = r2 >> 9, r3 = r2 & 511, lane = r3 >> 3, j = r3 & 7;
            int par = ct * 16 + (lane & 15), kpos = kt * 32 + ((lane >> 4) << 3) + j;
            int chi = cntf(i);
            float v = 0.0f;
            if (par < 25 && kpos < chi) v = Wout[(i * 25 + par) * 256 + porig(kpos)];
            WoutF[m] = (_Float16)v;
        } else if (e < 409600 + 512) {
            int m = e - 409600;
            int i = m >> 4, c = m & 15;
            int nn = cntf(i) - cntf(i - 1);
            b0F[m] = (c < nn) ? b0[c * 31 + i - 1] : 0.0f;
        } else if (e < 410112 + 512) {
            int m = e - 410112;
            int i = m >> 4, c = m & 15;
            int nn = cntf(i) - cntf(i - 1);
            b1F[m] = (c < nn) ? b1[c * 31 + i - 1] : 0.0f;
        } else {
            int m = e - 410624;
            int i = m >> 5, c = m & 31;
            boutF[m] = (c < 25) ? bout[i * 25 + c] : 0.0f;
        }
    }
}

// One wave per block; 16 rows per wave, all 32 AR steps, MACs on the matrix pipe.
// h0/h1 in LDS (frag-readable, XOR-swizzled). Spline cross-lane is all-DPP.
// Phase A is SOFTWARE-PIPELINED: its MFMA (over x_0..x_{i-1}) runs during the
// PREVIOUS step's spline; the missing k=i term is a rank-1 f32 VALU correction.
__global__ __launch_bounds__(64, 1) void inv_kernel(
    const float* __restrict__ z, const float* __restrict__ W0raw,
    const _Float16* __restrict__ W0F, const _Float16* __restrict__ W1F,
    const _Float16* __restrict__ WoutF,
    const float* __restrict__ b0F, const float* __restrict__ b1F,
    const float* __restrict__ boutF,
    const int* __restrict__ tstep_p,
    float* __restrict__ xout, float* __restrict__ ldj)
{
    __shared__ float zs[16 * 33];              // z tile  [16 rows][33] (padded)
    __shared__ float xs[16 * 33];              // x state [16 rows][33] (padded)
    __shared__ float ps[16 * 33];              // spline params per row (padded)
    __shared__ __align__(16) _Float16 h0L[16 * STRH];   // h0 state, frag layout
    __shared__ __align__(16) _Float16 h1L[16 * STRH];   // h1 state, frag layout

    const int l = threadIdx.x;
    const int c16 = l & 15;              // C/D col, B col, A row selector
    const int g = l >> 4;                // k-group
    const int row0 = blockIdx.x * 16;

    for (int idx = l; idx < 512; idx += 64) {
        int r = idx >> 5, c = idx & 31;
        zs[r * 33 + c] = z[row0 * 32 + idx];
    }
    {   // zero h0L/h1L (u32 stores)
        unsigned int* p0 = (unsigned int*)h0L;
        unsigned int* p1 = (unsigned int*)h1L;
        for (int idx = l; idx < 16 * STRH / 2; idx += 64) { p0[idx] = 0u; p1[idx] = 0u; }
    }

    f16x8 xfrag;                         // A-frag of x: row=c16, k=g*8+j
#pragma unroll
    for (int j = 0; j < 8; ++j) xfrag[j] = (_Float16)0.0f;

    const float alpha = fminf(fmaxf(((float)(*tstep_p)) / 10000.0f, 0.0f), 1.0f);
    const float oma = 1.0f - alpha;
    const float dxoff = logf(expm1f(0.9999f));   // DX_OFF (once, precise)

    float ldreg = 0.0f;

    // double-buffered Phase-A weights + biases; pipelined-A state
    f16x8 wa2[2];
    float b0v2[2], b1v2[2], boA2[2], boB2[2];
    float w0i2[2];                       // raw W0 row for the rank-1 correction
    f32x4 accA;                          // next step's A-MFMA partial (x_0..x_{i-1})
    f32x4 xi4;                           // x_i broadcast to this lane's 4 rows
    wa2[0] = *(const f16x8*)&W0F[l * 8];
    b0v2[0] = b0F[c16];
    b1v2[0] = b1F[c16];
    boA2[0] = boutF[c16];
    boB2[0] = boutF[16 + c16];
    w0i2[0] = 0.0f;
#pragma unroll
    for (int q = 0; q < 4; ++q) { accA[q] = 0.0f; xi4[q] = 0.0f; }

    FENCE_HW();   // zero-init / zs staging -> loop reads

#pragma unroll 1
    for (int ib = 0; ib < DD; ib += 2) {
#pragma unroll
        for (int ph = 0; ph < 2; ++ph) {
            const int i = ib + ph;
            const int clo = cntf(i - 1);
            const int chi = cntf(i);
            const int nn = chi - clo;        // 0 at i=0, else 8 or 9
            const int ip = (i + 1 < DD) ? (i + 1) : (DD - 1);

            // hoist zs read off the post-fence spline critical path
            const float zi = zs[(l >> 2) * 33 + i];

            // prefetch next step's A-weights + biases + raw-W0 correction row
            wa2[ph ^ 1] = *(const f16x8*)&W0F[ip * 512 + l * 8];
            b0v2[ph ^ 1] = b0F[ip * 16 + c16];
            b1v2[ph ^ 1] = b1F[ip * 16 + c16];
            boA2[ph ^ 1] = boutF[ip * 32 + c16];
            boB2[ph ^ 1] = boutF[ip * 32 + 16 + c16];
            {   // W0[k=i][c16*31 + i] (unit index for step i+1, slot c16); clamp OOB
                int widx = c16 * 31 + i;
                widx = (widx > 255) ? 255 : widx;
                w0i2[ph ^ 1] = W0raw[i * 256 + widx];
            }

            // this step's B/C weight frags (first use ~1 phase later; L2 covered)
            f16x8 wb_r[8], wc_r[2][8];
#pragma unroll
            for (int kt = 0; kt < 8; ++kt)
                wb_r[kt] = *(const f16x8*)&W1F[i * 4096 + kt * 512 + l * 8];
#pragma unroll
            for (int ct = 0; ct < 2; ++ct)
#pragma unroll
                for (int kt = 0; kt < 8; ++kt)
                    wc_r[ct][kt] = *(const f16x8*)&WoutF[i * 8192 + ct * 4096 + kt * 512 + l * 8];

            // ---- Phase A (pipelined): accA from last step + rank-1 x_{i-1} term ----
            if (nn > 0) {
                float bb = b0v2[ph];
                float w0i = w0i2[ph];
                if (c16 < nn) {
                    const int col = clo + c16;
#pragma unroll
                    for (int q = 0; q < 4; ++q) {
                        float v = accA[q] + xi4[q] * w0i + bb;
                        int row = g * 4 + q;
                        int phys = (col & ~31) | ((col & 31) ^ (8 * (row & 3)));
                        h0L[row * STRH + phys] = (_Float16)gelu_f(v);
                    }
                }
            }
            FENCE_HW();   // h0L writes -> Phase B frag reads

            // ---- Phase B: h1_new = gelu(h0_prefix @ W1_i); frags read from h0L ----
            if (nn > 0) {
                const int fbase = c16 * STRH + ((g ^ (c16 & 3)) << 3);
                f32x4 acc;
#pragma unroll
                for (int q = 0; q < 4; ++q) acc[q] = 0.0f;
#pragma unroll
                for (int kt = 0; kt < 8; ++kt) {
                    if (kt * 32 < chi) {
                        f16x8 af = *(const f16x8*)&h0L[fbase + kt * 32];
                        acc = __builtin_amdgcn_mfma_f32_16x16x32_f16(af, wb_r[kt], acc, 0, 0, 0);
                    }
                }
                float bb = b1v2[ph];
                if (c16 < nn) {
                    const int col = clo + c16;
#pragma unroll
                    for (int q = 0; q < 4; ++q) {
                        int row = g * 4 + q;
                        int phys = (col & ~31) | ((col & 31) ^ (8 * (row & 3)));
                        h1L[row * STRH + phys] = (_Float16)gelu_f(acc[q] + bb);
                    }
                }
            }
            FENCE_HW();   // h1L writes -> Phase C frag reads

            // ---- Phase C: p(16 rows x 25) = h1_prefix @ Wout_i + b_out ----
            {
                const int fbase = c16 * STRH + ((g ^ (c16 & 3)) << 3);
                f32x4 acc0, acc1;
#pragma unroll
                for (int q = 0; q < 4; ++q) { acc0[q] = 0.0f; acc1[q] = 0.0f; }
#pragma unroll
                for (int kt = 0; kt < 8; ++kt) {
                    if (kt * 32 < chi) {
                        f16x8 af = *(const f16x8*)&h1L[fbase + kt * 32];
                        acc0 = __builtin_amdgcn_mfma_f32_16x16x32_f16(af, wc_r[0][kt], acc0, 0, 0, 0);
                        acc1 = __builtin_amdgcn_mfma_f32_16x16x32_f16(af, wc_r[1][kt], acc1, 0, 0, 0);
                    }
                }
                float boA = boA2[ph], boB = boB2[ph];
#pragma unroll
                for (int q = 0; q < 4; ++q)
                    ps[(g * 4 + q) * 33 + c16] = acc0[q] + boA;
                if (16 + c16 < 25) {
#pragma unroll
                    for (int q = 0; q < 4; ++q)
                        ps[(g * 4 + q) * 33 + 16 + c16] = acc1[q] + boB;
                }
            }

            // ---- pipelined A-MFMA for NEXT step: overlaps the spline (MFMA pipe
            //      idle there). xfrag still lacks x_i here -> partial over x_0..x_{i-1}.
            {
                f32x4 zz;
#pragma unroll
                for (int q = 0; q < 4; ++q) zz[q] = 0.0f;
                accA = __builtin_amdgcn_mfma_f32_16x16x32_f16(xfrag, wa2[ph ^ 1], zz, 0, 0, 0);
            }
            FENCE_HW();   // ps writes -> spline reads

            // ---- Spline inverse: 4 lanes per row, all-DPP cross-lane ----
            float xv_sel;
            {
                const int r4 = l >> 2;          // row 0..15
                const int p  = l & 3;           // sub-lane in quad

                const float* bp = &ps[r4 * 33];
                float w_a = bp[p],      w_b = bp[4 + p];
                float h_a = bp[8 + p],  h_b = bp[12 + p];
                float d_a = bp[16 + p], d_b = bp[20 + p], d_cin = bp[24];

                // widths softmax chain (2 bins per lane); 2nd max-shift dropped
                float m_w = qmax2(fmaxf(w_a, w_b));
                float ewa = __expf(w_a - m_w), ewb = __expf(w_b - m_w);
                float rsw = rcp_f(qsum2(ewa + ewb));
                float bwa = oma * 1.25f + alpha * (ewa * rsw * 9.92f + 0.001f);
                float bwb = oma * 1.25f + alpha * (ewb * rsw * 9.92f + 0.001f);
                float scw = 10.0f * rcp_f(qsum2(bwa + bwb));
                bwa *= scw; bwb *= scw;
                float e2wa = __expf(bwa), e2wb = __expf(bwb);
                float rs2w = rcp_f(qsum2(e2wa + e2wb));
                float wdt_a = e2wa * rs2w * 9.9992f + 1e-4f;
                float wdt_b = e2wb * rs2w * 9.9992f + 1e-4f;

                // heights softmax chain
                float m_h = qmax2(fmaxf(h_a, h_b));
                float eha = __expf(h_a - m_h), ehb = __expf(h_b - m_h);
                float rsh = rcp_f(qsum2(eha + ehb));
                float bha = oma * 1.25f + alpha * (eha * rsh * 9.92f + 0.001f);
                float bhb = oma * 1.25f + alpha * (ehb * rsh * 9.92f + 0.001f);
                float sch = 10.0f * rcp_f(qsum2(bha + bhb));
                bha *= sch; bhb *= sch;
                float e2ha = __expf(bha), e2hb = __expf(bhb);
                float rs2h = rcp_f(qsum2(e2ha + e2hb));
                float hgt_a = e2ha * rs2h * 9.9992f + 1e-4f;
                float hgt_b = e2hb * rs2h * 9.9992f + 1e-4f;

                // slopes
                float dsl_a = softplus_f(oma + alpha * (softplus_f(d_a) + 0.001f) + dxoff) + 1e-4f;
                float dsl_b = softplus_f(oma + alpha * (softplus_f(d_b) + 0.001f) + dxoff) + 1e-4f;
                float dsl_c = softplus_f(oma + alpha * (softplus_f(d_cin) + 0.001f) + dxoff) + 1e-4f;

                // inclusive cumsums over 8 bins (DPP quad scans; b-half += a-total)
                float ca  = qscan(wdt_a, p);
                float cb  = qscan(wdt_b, p) + qperm<0xFF>(ca);
                float cha = qscan(hgt_a, p);
                float chb = qscan(hgt_b, p) + qperm<0xFF>(cha);

                // materialize all quad elements per lane (reg m holds elem p^m)
                float wdA1 = qperm<0xB1>(wdt_a), wdA2 = qperm<0x4E>(wdt_a), wdA3 = qperm<0x1B>(wdt_a);
                float wdB1 = qperm<0xB1>(wdt_b), wdB2 = qperm<0x4E>(wdt_b), wdB3 = qperm<0x1B>(wdt_b);
                float hgA1 = qperm<0xB1>(hgt_a), hgA2 = qperm<0x4E>(hgt_a), hgA3 = qperm<0x1B>(hgt_a);
                float hgB1 = qperm<0xB1>(hgt_b), hgB2 = qperm<0x4E>(hgt_b), hgB3 = qperm<0x1B>(hgt_b);
                float dsA1 = qperm<0xB1>(dsl_a), dsA2 = qperm<0x4E>(dsl_a), dsA3 = qperm<0x1B>(dsl_a);
                float dsB1 = qperm<0xB1>(dsl_b), dsB2 = qperm<0x4E>(dsl_b), dsB3 = qperm<0x1B>(dsl_b);
                float caA1 = qperm<0xB1>(ca),    caA2 = qperm<0x4E>(ca),    caA3 = qperm<0x1B>(ca);
                float caB1 = qperm<0xB1>(cb),    caB2 = qperm<0x4E>(cb),    caB3 = qperm<0x1B>(cb);
                float chA1 = qperm<0xB1>(cha),   chA2 = qperm<0x4E>(cha),   chA3 = qperm<0x1B>(cha);
                float chB1 = qperm<0xB1>(chb),   chB2 = qperm<0x4E>(chb),   chB3 = qperm<0x1B>(chb);

                const bool inr = (zi >= -5.0f) && (zi <= 5.0f);
                const float yc = fminf(fmaxf(zi, -5.0f), 5.0f);

                // bin index: count knots yp[e]<=yc over e=0..6 (exclude bin-7 knot)
                float ch7 = qperm<0xFF>(chb);
                int cnt = 0;
                cnt += (yc >= cha  - 5.0f); cnt += (yc >= chA1 - 5.0f);
                cnt += (yc >= chA2 - 5.0f); cnt += (yc >= chA3 - 5.0f);
                cnt += (yc >= chb  - 5.0f); cnt += (yc >= chB1 - 5.0f);
                cnt += (yc >= chB2 - 5.0f); cnt += (yc >= chB3 - 5.0f);
                int idx = cnt - ((yc >= ch7 - 5.0f) ? 1 : 0);   // 0..7

                // gather knot quantities via register select trees (no bpermute)
                int mA = (idx & 3) ^ p;
                bool hiH = (idx >= 4);
                float wk = hiH ? sel4(wdt_b, wdB1, wdB2, wdB3, mA)
                               : sel4(wdt_a, wdA1, wdA2, wdA3, mA);
                float hk = hiH ? sel4(hgt_b, hgB1, hgB2, hgB3, mA)
                               : sel4(hgt_a, hgA1, hgA2, hgA3, mA);
                float dk = hiH ? sel4(dsl_b, dsB1, dsB2, dsB3, mA)
                               : sel4(dsl_a, dsA1, dsA2, dsA3, mA);
                int j1 = idx + 1;
                int mJ = (j1 & 3) ^ p;
                float d1A = sel4(dsl_a, dsA1, dsA2, dsA3, mJ);
                float d1B = sel4(dsl_b, dsB1, dsB2, dsB3, mJ);
                float dk1 = (j1 < 4) ? d1A : ((j1 < 8) ? d1B : dsl_c);
                int im1 = idx - 1;
                int mM = (im1 & 3) ^ p;
                float cwm = (im1 < 4) ? sel4(ca, caA1, caA2, caA3, mM)
                                      : sel4(cb, caB1, caB2, caB3, mM);
                float chm = (im1 < 4) ? sel4(cha, chA1, chA2, chA3, mM)
                                      : sel4(chb, chB1, chB2, chB3, mM);
                float xk = (idx == 0) ? -5.0f : (cwm - 5.0f);
                float yk = (idx == 0) ? -5.0f : (chm - 5.0f);

                // rational-quadratic inverse (redundant on the quad)
                float s_ = hk * rcp_f(wk);
                float tt = yc - yk;
                float coef = dk1 + dk - 2.0f * s_;
                float aa = hk * (s_ - dk) + tt * coef;
                float bb = hk * dk - tt * coef;
                float cc = -s_ * tt;
                float disc = bb * bb - 4.0f * aa * cc;
                float xi = 2.0f * cc * rcp_f(-bb - __builtin_amdgcn_sqrtf(disc));
                float xv = xi * wk + xk;
                float z1 = xi * (1.0f - xi);
                float den = s_ + coef * z1;
                float omxi = 1.0f - xi;
                float num = dk1 * xi * xi + 2.0f * s_ * z1 + dk * omxi * omxi;
                float ld = __logf(den * den * rcp_f(s_ * s_ * num));  // fused 3-log

                xv_sel = inr ? xv : zi;
                ldreg += inr ? ld : 0.0f;
                if (p == 0) xs[(l >> 2) * 33 + i] = xv_sel;
            }

            // broadcast new x_i: rank-1 correction rows (xi4) + xfrag update
            {
#pragma unroll
                for (int q = 0; q < 4; ++q)
                    xi4[q] = __shfl(xv_sel, (g * 4 + q) << 2);
                float xnew = __shfl(xv_sel, (l & 15) << 2);
                if (g == (i >> 3)) {
#pragma unroll
                    for (int j = 0; j < 8; ++j)
                        if (j == (i & 7)) xfrag[j] = (_Float16)xnew;
                }
            }
            FENCE_C();
        }
    }

    FENCE_HW();   // xs writes -> output reads
    for (int idx = l; idx < 512; idx += 64) {
        int r = idx >> 5, c = idx & 31;
        xout[row0 * 32 + idx] = xs[r * 33 + c];
    }
    if ((l & 3) == 0) ldj[row0 + (l >> 2)] = ldreg;
}

extern "C" void kernel_launch(void* const* d_in, const int* in_sizes, int n_in,
                              void* d_out, int out_size, void* d_ws, size_t ws_size,
                              hipStream_t stream)
{
    const float* z    = (const float*)d_in[0];
    const float* W0   = (const float*)d_in[1];
    const float* b0   = (const float*)d_in[2];
    const float* W1   = (const float*)d_in[3];
    const float* b1   = (const float*)d_in[4];
    const float* Wout = (const float*)d_in[5];
    const float* bout = (const float*)d_in[6];
    const int* tstep  = (const int*)d_in[8];

    float* out  = (float*)d_out;
    float* xout = out;                 // x_fin, B x D
    float* ldj  = out + NB * DD;       // ldj, B

    _Float16* W0F   = (_Float16*)d_ws;            // 16384 halfs
    _Float16* W1F   = W0F + 16384;                // 131072 halfs
    _Float16* WoutF = W1F + 131072;               // 262144 halfs
    float* b0F  = (float*)(WoutF + 262144);       // 512 f32
    float* b1F  = b0F + 512;                      // 512 f32
    float* boutF = b1F + 512;                     // 1024 f32

    prep_kernel<<<1608, 256, 0, stream>>>(W0, b0, W1, b1, Wout, bout,
                                          W0F, W1F, WoutF, b0F, b1F, boutF);
    inv_kernel<<<NB / 16, 64, 0, stream>>>(z, W0, W0F, W1F, WoutF, b0F, b1F, boutF,
                                           tstep, xout, ldj);
}